// Round 1
// baseline (263.186 us; speedup 1.0000x reference)
//
#include <hip/hip_runtime.h>
#include <math.h>

constexpr int T_TOK = 16384;
constexpr int HDIM  = 2048;
constexpr int NEXP  = 64;
constexpr int TPB   = 32;            // tokens per block (halved -> 512 blocks, 2 per CU)
constexpr int MT    = TPB / 16;      // 2 m-tiles of 16 tokens
constexpr int NWAVE = 8;
constexpr int KPW   = HDIM / NWAVE;  // 256 k per wave
constexpr int KSTEP = 32;
constexpr int NKS   = KPW / KSTEP;   // 8 k-steps

typedef __attribute__((ext_vector_type(8))) short v8s;   // 8 bf16 (4 VGPRs)
typedef __attribute__((ext_vector_type(4))) float v4f;   // 4 fp32 acc

#define MFMA_BF16 __builtin_amdgcn_mfma_f32_16x16x32_bf16

// Dekker-style truncation split: x = h + m + l exactly to ~24 mantissa bits.
static __device__ __forceinline__ void split3(float x, unsigned short& h,
                                              unsigned short& m, unsigned short& l)
{
    unsigned u0 = __float_as_uint(x);
    h = (unsigned short)(u0 >> 16);
    float r1 = x - __uint_as_float(u0 & 0xFFFF0000u);     // exact
    unsigned u1 = __float_as_uint(r1);
    m = (unsigned short)(u1 >> 16);
    float r2 = r1 - __uint_as_float(u1 & 0xFFFF0000u);    // exact
    l = (unsigned short)(__float_as_uint(r2) >> 16);
}

static __device__ __forceinline__ void frag3(const float4& x0, const float4& x1,
                                             v8s& h, v8s& m, v8s& l)
{
    unsigned short sh, sm, sl;
    split3(x0.x, sh, sm, sl); h[0]=(short)sh; m[0]=(short)sm; l[0]=(short)sl;
    split3(x0.y, sh, sm, sl); h[1]=(short)sh; m[1]=(short)sm; l[1]=(short)sl;
    split3(x0.z, sh, sm, sl); h[2]=(short)sh; m[2]=(short)sm; l[2]=(short)sl;
    split3(x0.w, sh, sm, sl); h[3]=(short)sh; m[3]=(short)sm; l[3]=(short)sl;
    split3(x1.x, sh, sm, sl); h[4]=(short)sh; m[4]=(short)sm; l[4]=(short)sl;
    split3(x1.y, sh, sm, sl); h[5]=(short)sh; m[5]=(short)sm; l[5]=(short)sl;
    split3(x1.z, sh, sm, sl); h[6]=(short)sh; m[6]=(short)sm; l[6]=(short)sl;
    split3(x1.w, sh, sm, sl); h[7]=(short)sh; m[7]=(short)sm; l[7]=(short)sl;
}

// swizzled expert column for the LDS reduction buffer (breaks 4-way write conflicts)
static __device__ __forceinline__ int swz_e(int tok, int e) {
    return e ^ (((tok >> 2) & 1) << 4);
}

__global__ __launch_bounds__(512, 4)
void moe_router_mfma(const float* __restrict__ X,
                     const float* __restrict__ Wg,
                     const float* __restrict__ Bg,
                     float* __restrict__ out)
{
    __shared__ float red[4][TPB][NEXP];    // 32 KiB, epilogue only

    const int tid  = threadIdx.x;
    const int lane = tid & 63;
    const int wv   = tid >> 6;             // wave id = k-slice
    const int r16  = lane & 15;
    const int q    = lane >> 4;            // quad id (k-chunk selector)
    const int tok0 = blockIdx.x * TPB;

    // A: lane reads X[tok0 + 16*mt + r16][wv*256 + ks*32 + q*8 .. +7]
    const float* pA = X  + (size_t)(tok0 + r16) * HDIM + wv * KPW + q * 8;
    // B: lane reads W[16*nt + r16][same k window]
    const float* pB = Wg + (size_t)r16 * HDIM + wv * KPW + q * 8;

    v4f acc[MT][4];
#pragma unroll
    for (int mt = 0; mt < MT; ++mt)
#pragma unroll
        for (int nt = 0; nt < 4; ++nt)
            acc[mt][nt] = (v4f){0.f, 0.f, 0.f, 0.f};

    float4 a0[MT], a1[MT], b0[4], b1[4];
#pragma unroll
    for (int mt = 0; mt < MT; ++mt) {
        const float* p = pA + (size_t)mt * 16 * HDIM;
        a0[mt] = *(const float4*)p;
        a1[mt] = *(const float4*)(p + 4);
    }
#pragma unroll
    for (int nt = 0; nt < 4; ++nt) {
        const float* p = pB + (size_t)nt * 16 * HDIM;
        b0[nt] = *(const float4*)p;
        b1[nt] = *(const float4*)(p + 4);
    }

    for (int ks = 0; ks < NKS; ++ks) {
        // ---- split current fp32 buffers into bf16 frag triples
        v8s Ah[MT], Am[MT], Al[MT], Bh[4], Bm[4], Bl[4];
#pragma unroll
        for (int mt = 0; mt < MT; ++mt) frag3(a0[mt], a1[mt], Ah[mt], Am[mt], Al[mt]);
#pragma unroll
        for (int nt = 0; nt < 4; ++nt) frag3(b0[nt], b1[nt], Bh[nt], Bm[nt], Bl[nt]);

        // ---- prefetch next k-step (covers HBM latency under the MFMA block)
        if (ks < NKS - 1) {
            const int off = (ks + 1) * KSTEP;
#pragma unroll
            for (int mt = 0; mt < MT; ++mt) {
                const float* p = pA + (size_t)mt * 16 * HDIM + off;
                a0[mt] = *(const float4*)p;
                a1[mt] = *(const float4*)(p + 4);
            }
#pragma unroll
            for (int nt = 0; nt < 4; ++nt) {
                const float* p = pB + (size_t)nt * 16 * HDIM + off;
                b0[nt] = *(const float4*)p;
                b1[nt] = *(const float4*)(p + 4);
            }
        }

        // ---- 6-product split GEMM: hh + hm + mh + hl + lh + mm
#pragma unroll
        for (int mt = 0; mt < MT; ++mt)
#pragma unroll
            for (int nt = 0; nt < 4; ++nt) {
                v4f a = acc[mt][nt];
                a = MFMA_BF16(Ah[mt], Bh[nt], a, 0, 0, 0);
                a = MFMA_BF16(Ah[mt], Bm[nt], a, 0, 0, 0);
                a = MFMA_BF16(Am[mt], Bh[nt], a, 0, 0, 0);
                a = MFMA_BF16(Ah[mt], Bl[nt], a, 0, 0, 0);
                a = MFMA_BF16(Al[mt], Bh[nt], a, 0, 0, 0);
                a = MFMA_BF16(Am[mt], Bm[nt], a, 0, 0, 0);
                acc[mt][nt] = a;
            }
    }

    // ---- cross-wave K reduction: 4 slots, two phases
    // C/D layout: col(expert-local) = lane&15, row(token-local) = q*4 + r
    if (wv < 4) {
#pragma unroll
        for (int mt = 0; mt < MT; ++mt)
#pragma unroll
            for (int nt = 0; nt < 4; ++nt)
#pragma unroll
                for (int r = 0; r < 4; ++r) {
                    int tok = 16 * mt + q * 4 + r;
                    int e   = 16 * nt + r16;
                    red[wv][tok][swz_e(tok, e)] = acc[mt][nt][r];
                }
    }
    __syncthreads();
    if (wv >= 4) {
#pragma unroll
        for (int mt = 0; mt < MT; ++mt)
#pragma unroll
            for (int nt = 0; nt < 4; ++nt)
#pragma unroll
                for (int r = 0; r < 4; ++r) {
                    int tok = 16 * mt + q * 4 + r;
                    int e   = 16 * nt + r16;
                    red[wv - 4][tok][swz_e(tok, e)] += acc[mt][nt][r];
                }
    }
    __syncthreads();

    // ---- epilogue: 4 tokens/wave on lanes 0..3
    // lg[] is indexed by eo (STATIC, stays in registers); expert id is
    // e = (eo + 16*lane) & 63 — the per-lane rotation staggers LDS banks
    // (tk stride is 64 floats -> all lanes same bank without it).
    if (lane < 4) {
        const int tk = wv * 4 + lane;
        const int t  = tok0 + tk;
        const int sh = lane << 4;            // 0,16,32,48
        float lg[NEXP];
#pragma unroll
        for (int eo = 0; eo < NEXP; ++eo) {
            int e  = (eo + sh) & (NEXP - 1);
            int es = swz_e(tk, e);
            lg[eo] = ((red[0][tk][es] + red[1][tk][es]) +
                      (red[2][tk][es] + red[3][tk][es])) + Bg[e];
        }
        float* outL = out + (size_t)t * NEXP;
#pragma unroll
        for (int eo = 0; eo < NEXP; eo += 4) {
            int e = (eo + sh) & (NEXP - 1);  // sh is a multiple of 16 -> e 4-aligned blocks stay contiguous
            float4 v = make_float4(lg[eo], lg[eo+1], lg[eo+2], lg[eo+3]);
            *(float4*)(outL + e) = v;
        }
        // softmax + top-2 are permutation-invariant over eo; map indices back at the end
        float mx = lg[0];
#pragma unroll
        for (int eo = 1; eo < NEXP; ++eo) mx = fmaxf(mx, lg[eo]);
        float S = 0.f;
#pragma unroll
        for (int eo = 0; eo < NEXP; ++eo) { lg[eo] = expf(lg[eo] - mx); S += lg[eo]; }
#pragma unroll
        for (int eo = 0; eo < NEXP; ++eo) lg[eo] = lg[eo] / S;

        float v1 = lg[0]; int i1o = 0;
        float v2 = -1.0f; int i2o = 0;
#pragma unroll
        for (int eo = 1; eo < NEXP; ++eo) {
            float rv = lg[eo];
            bool g1 = rv > v1;
            bool g2 = rv > v2;
            float nv2 = g1 ? v1 : (g2 ? rv : v2);
            int   ni2 = g1 ? i1o : (g2 ? eo : i2o);
            v2 = nv2; i2o = ni2;
            v1 = g1 ? rv : v1;
            i1o = g1 ? eo : i1o;
        }
        const int i1 = (i1o + sh) & (NEXP - 1);
        const int i2 = (i2o + sh) & (NEXP - 1);
        float den = v1 + v2;
        float w1 = v1 / den, w2 = v2 / den;

        float* outW = out + (size_t)T_TOK * NEXP;
        float* outS = outW + (size_t)T_TOK * 2;
        float* outM = outS + (size_t)T_TOK * 2;
        outW[2*t+0] = w1;        outW[2*t+1] = w2;
        outS[2*t+0] = (float)i1; outS[2*t+1] = (float)i2;

        float* mrow = outM + (size_t)t * 2 * NEXP;
#pragma unroll
        for (int e = 0; e < NEXP; e += 4) {
            float4 a = make_float4(e+0==i1?1.f:0.f, e+1==i1?1.f:0.f,
                                   e+2==i1?1.f:0.f, e+3==i1?1.f:0.f);
            *(float4*)(mrow + e) = a;
            float4 b = make_float4(e+0==i2?1.f:0.f, e+1==i2?1.f:0.f,
                                   e+2==i2?1.f:0.f, e+3==i2?1.f:0.f);
            *(float4*)(mrow + NEXP + e) = b;
        }
    }
}

extern "C" void kernel_launch(void* const* d_in, const int* in_sizes, int n_in,
                              void* d_out, int out_size, void* d_ws, size_t ws_size,
                              hipStream_t stream)
{
    const float* X = (const float*)d_in[0];
    const float* W = (const float*)d_in[1];
    const float* B = (const float*)d_in[2];
    float* out     = (float*)d_out;

    dim3 grid(T_TOK / TPB);   // 512 blocks -> 2 per CU (16 waves/CU resident)
    dim3 block(512);          // 8 waves
    hipLaunchKernelGGL(moe_router_mfma, grid, block, 0, stream, X, W, B, out);
}